// Round 10
// baseline (286.626 us; speedup 1.0000x reference)
//
#include <hip/hip_runtime.h>
#include <math.h>
#include <stdint.h>

typedef unsigned short u16;
typedef __bf16 bf16x8 __attribute__((ext_vector_type(8)));
typedef float  f32x4  __attribute__((ext_vector_type(4)));

#define AS1 __attribute__((address_space(1)))
#define AS3 __attribute__((address_space(3)))

__device__ __forceinline__ void gld_lds16(const void* g, void* l) {
    // async global->LDS, 16B per lane; LDS dest = wave-uniform base + lane*16
    __builtin_amdgcn_global_load_lds((AS1 const uint32_t*)g, (AS3 uint32_t*)l, 16, 0, 0);
}

__device__ __forceinline__ u16 f2bf(float f) {   // RNE
    unsigned u = __float_as_uint(f);
    unsigned r = u + 0x7fffu + ((u >> 16) & 1u);
    return (u16)(r >> 16);
}

namespace {
constexpr int Tc  = 2048;
constexpr int Hc  = 16;
constexpr size_t QE = 8388608;   // B*H*T*64 elems
}

// ---------------------------------------------------------------------------
// Fused converts (1 launch instead of 3):
//   blocks 0..4095   : x fp32 -> bf16 flat (8 elems/thread, exact cover)
//   blocks 4096..4863: w_qkv  [1024][3072] -> bf16 [3072][1024] transpose
//   blocks 4864..5119: w_proj [1024][1024] -> bf16 [1024][1024] transpose
// ---------------------------------------------------------------------------
__global__ __launch_bounds__(256) void cvt_fused(
    const float* __restrict__ x, const float* __restrict__ wq,
    const float* __restrict__ wp,
    u16* __restrict__ xb, u16* __restrict__ wqT, u16* __restrict__ wpT)
{
    __shared__ u16 t[64][72];
    const int b   = blockIdx.x;
    const int tid = threadIdx.x;

    if (b < 4096) {   // flat convert: 4096*256 threads == 1048576 == exact
        int i = b * 256 + tid;
        const float4* p = (const float4*)x + (size_t)i * 2;
        float4 a = p[0], bb = p[1];
        union { u16 u[8]; uint4 v; } r;
        r.u[0] = f2bf(a.x);  r.u[1] = f2bf(a.y);
        r.u[2] = f2bf(a.z);  r.u[3] = f2bf(a.w);
        r.u[4] = f2bf(bb.x); r.u[5] = f2bf(bb.y);
        r.u[6] = f2bf(bb.z); r.u[7] = f2bf(bb.w);
        ((uint4*)xb)[i] = r.v;
        return;
    }

    const float* src;
    u16* dst;
    int N, bx, by;
    if (b < 4864) { int l = b - 4096; N = 3072; src = wq; dst = wqT; bx = l % 48; by = l / 48; }
    else          { int l = b - 4864; N = 1024; src = wp; dst = wpT; bx = l % 16; by = l / 16; }

    const int n0 = bx * 64, k0 = by * 64;
    const int r  = tid >> 2, c0 = (tid & 3) << 4;
    const float* s = src + (size_t)(k0 + r) * N + n0 + c0;
#pragma unroll
    for (int j = 0; j < 16; j += 4) {
        float4 f = *(const float4*)(s + j);
        t[r][c0 + j + 0] = f2bf(f.x);
        t[r][c0 + j + 1] = f2bf(f.y);
        t[r][c0 + j + 2] = f2bf(f.z);
        t[r][c0 + j + 3] = f2bf(f.w);
    }
    __syncthreads();
    u16* d = dst + (size_t)(n0 + r) * 1024 + k0 + c0;
    union { u16 u[8]; uint4 v; } o1, o2;
#pragma unroll
    for (int j = 0; j < 8; ++j) o1.u[j] = t[c0 + j][r];
#pragma unroll
    for (int j = 0; j < 8; ++j) o2.u[j] = t[c0 + 8 + j][r];
    *(uint4*)d = o1.v;
    *(uint4*)(d + 8) = o2.v;
}

// ---------------------------------------------------------------------------
// QKV GEMM: [8192,1024]bf16 @ [1024,3072] (B^T layout [3072][1024]) -> q/k/vT
// 128x128 tile, BK=32, 4 waves, 16x16x32 MFMA.
// Triple-buffer LDS + counted s_waitcnt vmcnt(4) + raw s_barrier.
// R10: 1D grid with XCD-chunked bijective swizzle (1536 = 8 x 192), n-major
// decode: each XCD owns 3 contiguous B-panels (768 KB, L2-resident).
// ---------------------------------------------------------------------------
__global__ __launch_bounds__(256) void qkv_gemm_bf16(
    const u16* __restrict__ xb, const u16* __restrict__ wT,
    const float* __restrict__ bias,
    u16* __restrict__ qo, u16* __restrict__ ko, u16* __restrict__ vt)
{
    __shared__ u16 At[3][4096];
    __shared__ u16 Bt[3][4096];

    const int tid  = threadIdx.x;
    const int lane = tid & 63;
    const int wv   = tid >> 6;
    const int wr   = wv >> 1;
    const int wc   = wv & 1;
    const int bsw  = (int)blockIdx.x;
    const int w    = (bsw & 7) * 192 + (bsw >> 3);   // XCD-chunked, bijective
    const int m0   = (w & 63) * 128;
    const int n0   = (w >> 6) * 128;

    const int p1 = wv * 128 + lane, p2 = p1 + 64;
    const int r1 = p1 >> 2, c1 = (p1 & 3) ^ ((r1 >> 1) & 3);
    const int r2 = p2 >> 2, c2 = (p2 & 3) ^ ((r2 >> 1) & 3);

    const u16* ga1 = xb + (size_t)(m0 + r1) * 1024 + c1 * 8;
    const u16* ga2 = xb + (size_t)(m0 + r2) * 1024 + c2 * 8;
    const u16* gb1 = wT + (size_t)(n0 + r1) * 1024 + c1 * 8;
    const u16* gb2 = wT + (size_t)(n0 + r2) * 1024 + c2 * 8;

    f32x4 acc[4][4] = {};

#define STAGE_G(buf, k0)                                   \
    do {                                                   \
        gld_lds16(ga1 + (k0), &At[buf][wv * 1024]);        \
        gld_lds16(ga2 + (k0), &At[buf][wv * 1024 + 512]);  \
        gld_lds16(gb1 + (k0), &Bt[buf][wv * 1024]);        \
        gld_lds16(gb2 + (k0), &Bt[buf][wv * 1024 + 512]);  \
    } while (0)

    auto COMPUTE = [&](int bsel) {
        bf16x8 af[4], bfr[4];
#pragma unroll
        for (int i = 0; i < 4; ++i) {
            int row = wr * 64 + i * 16 + (lane & 15);
            int c   = (lane >> 4) ^ ((row >> 1) & 3);
            af[i] = *(const bf16x8*)&At[bsel][row * 32 + c * 8];
            int rowb = wc * 64 + i * 16 + (lane & 15);
            int cb   = (lane >> 4) ^ ((rowb >> 1) & 3);
            bfr[i] = *(const bf16x8*)&Bt[bsel][rowb * 32 + cb * 8];
        }
#pragma unroll
        for (int i = 0; i < 4; ++i)
#pragma unroll
            for (int j = 0; j < 4; ++j)
                acc[i][j] = __builtin_amdgcn_mfma_f32_16x16x32_bf16(
                    af[i], bfr[j], acc[i][j], 0, 0, 0);
    };

    STAGE_G(0, 0);
    STAGE_G(1, 32);
    int b0 = 0, b1 = 1, b2 = 2;
    for (int t = 0; t < 31; ++t) {
        asm volatile("s_waitcnt vmcnt(4)" ::: "memory");  // own stage(t) landed
        __builtin_amdgcn_s_barrier();                     // everyone's landed
        asm volatile("" ::: "memory");
        if (t < 30) STAGE_G(b2, (t + 2) * 32);
        COMPUTE(b0);
        int tmp = b0; b0 = b1; b1 = b2; b2 = tmp;
    }
    asm volatile("s_waitcnt vmcnt(0)" ::: "memory");
    __builtin_amdgcn_s_barrier();
    asm volatile("" ::: "memory");
    COMPUTE(b0);
#undef STAGE_G

    const int nq = n0 + wc * 64;
    const int which = nq >> 10;
    const int h  = (nq & 1023) >> 6;
    const int rr = (lane >> 4) * 4;
    const int cl = lane & 15;

    if (which < 2) {
        u16* dst = which ? ko : qo;
#pragma unroll
        for (int i = 0; i < 4; ++i)
#pragma unroll
            for (int j = 0; j < 4; ++j) {
                int d = j * 16 + cl;
                float bv = bias[nq + d];
#pragma unroll
                for (int r = 0; r < 4; ++r) {
                    int m = m0 + wr * 64 + i * 16 + rr + r;
                    int b = m >> 11, tt = m & 2047;
                    dst[(((size_t)(b * Hc + h)) * Tc + tt) * 64 + d] =
                        f2bf(acc[i][j][r] + bv);
                }
            }
    } else {
        // V stored TRANSPOSED: vt[bh][d][t]
#pragma unroll
        for (int i = 0; i < 4; ++i) {
            int m = m0 + wr * 64 + i * 16 + rr;
            int b = m >> 11, tt = m & 2047;
#pragma unroll
            for (int j = 0; j < 4; ++j) {
                int d = j * 16 + cl;
                float bv = bias[nq + d];
                union { u16 u[4]; uint2 v2; } pk;
#pragma unroll
                for (int r = 0; r < 4; ++r) pk.u[r] = f2bf(acc[i][j][r] + bv);
                *(uint2*)&vt[((size_t)(b * Hc + h) * 64 + d) * Tc + tt] = pk.v2;
            }
        }
    }
}

// ---------------------------------------------------------------------------
// Flash attention v5: 128 q-rows/block (32/wave), Q pre-scaled in registers,
// K/V dbuf swizzled LDS, setprio around MFMA, max-free softmax (bounded S),
// lane-local deferred li. Grid already XCD-friendly: b%8 == bh%8, all 16
// q-blocks of a head land on one XCD (K/V L2-shared).
// ---------------------------------------------------------------------------
__global__ __launch_bounds__(256, 3) void flash_mfma(
    const u16* __restrict__ qg, const u16* __restrict__ kg,
    const u16* __restrict__ vtg, u16* __restrict__ og)
{
    __shared__ u16 Ks[2][4096];
    __shared__ u16 Vs[2][4096];
    __shared__ u16 Ps[8192];     // 4 waves x 32 rows x 64 (swizzled)

    const int tid  = threadIdx.x;
    const int lane = tid & 63;
    const int wv   = tid >> 6;
    const int qb   = 15 - (int)(blockIdx.x >> 6);   // qb-major, heavy first
    const int bh   = blockIdx.x & 63;

    const int p1 = wv * 128 + lane, p2 = p1 + 64;
    const int r1 = p1 >> 3, c1 = (p1 & 7) ^ (r1 & 7);
    const int r2 = p2 >> 3, c2 = (p2 & 7) ^ (r2 & 7);

    const size_t tb = (size_t)bh * Tc;
    const u16* kb1 = kg + (tb + r1) * 64 + c1 * 8;
    const u16* kb2 = kg + (tb + r2) * 64 + c2 * 8;
    const u16* vb1 = vtg + ((size_t)bh * 64 + r1) * Tc + c1 * 8;
    const u16* vb2 = vtg + ((size_t)bh * 64 + r2) * Tc + c2 * 8;

    // ---- Q -> registers, pre-scaled by 1/8 (exact in bf16)
    bf16x8 qr[2][2];
    {
        const u16* qbase = qg + (tb + (size_t)qb * 128 + wv * 32) * 64;
#pragma unroll
        for (int ar = 0; ar < 2; ++ar)
#pragma unroll
            for (int ks = 0; ks < 2; ++ks) {
                union { bf16x8 v; u16 u[8]; uint4 q; } t;
                t.q = *(const uint4*)(qbase + (ar * 16 + (lane & 15)) * 64 +
                                      ks * 32 + (lane >> 4) * 8);
#pragma unroll
                for (int j = 0; j < 8; ++j) {
                    float f = __uint_as_float((unsigned)t.u[j] << 16) * 0.125f;
                    t.u[j] = f2bf(f);
                }
                qr[ar][ks] = t.v;
            }
    }

    gld_lds16(kb1, &Ks[0][wv * 1024]);
    gld_lds16(kb2, &Ks[0][wv * 1024 + 512]);
    gld_lds16(vb1, &Vs[0][wv * 1024]);
    gld_lds16(vb2, &Vs[0][wv * 1024 + 512]);
    asm volatile("s_waitcnt vmcnt(0)" ::: "memory");
    __syncthreads();

    f32x4 accO[2][4] = {};
    float li[2][4] = {};

    const int nt = 2 * qb + 2;
    int cur = 0;

    for (int kt = 0; kt < nt; ++kt) {
        if (kt + 1 < nt) {
            int nx = kt + 1;
            gld_lds16(kb1 + (size_t)nx * 4096, &Ks[cur ^ 1][wv * 1024]);
            gld_lds16(kb2 + (size_t)nx * 4096, &Ks[cur ^ 1][wv * 1024 + 512]);
            gld_lds16(vb1 + nx * 64, &Vs[cur ^ 1][wv * 1024]);
            gld_lds16(vb2 + nx * 64, &Vs[cur ^ 1][wv * 1024 + 512]);
        }

        // waves 0/1 are fully masked on the final (odd) diagonal tile
        const bool skip = (kt == 2 * qb + 1) && (wv < 2);
        if (!skip) {
            // ---- S = Q K^T : per wave 32 q-rows x 64 keys
            f32x4 s4[2][4] = {};
            __builtin_amdgcn_s_setprio(1);
#pragma unroll
            for (int ks = 0; ks < 2; ++ks) {
                bf16x8 bk[4];
#pragma unroll
                for (int nf = 0; nf < 4; ++nf) {
                    int brow = nf * 16 + (lane & 15);
                    int bc   = (ks * 4 + (lane >> 4)) ^ (brow & 7);
                    bk[nf] = *(const bf16x8*)&Ks[cur][brow * 64 + bc * 8];
                }
#pragma unroll
                for (int ar = 0; ar < 2; ++ar)
#pragma unroll
                    for (int nf = 0; nf < 4; ++nf)
                        s4[ar][nf] = __builtin_amdgcn_mfma_f32_16x16x32_bf16(
                            qr[ar][ks], bk[nf], s4[ar][nf], 0, 0, 0);
            }
            __builtin_amdgcn_s_setprio(0);

            if (kt >= 2 * qb) {   // diagonal region: mask key > q
#pragma unroll
                for (int ar = 0; ar < 2; ++ar)
#pragma unroll
                    for (int nf = 0; nf < 4; ++nf)
#pragma unroll
                        for (int r = 0; r < 4; ++r) {
                            int key  = kt * 64 + nf * 16 + (lane & 15);
                            int qrow = qb * 128 + wv * 32 + ar * 16 +
                                       (lane >> 4) * 4 + r;
                            if (key > qrow) s4[ar][nf][r] = -INFINITY;
                        }
            }

            // ---- softmax numerator, no max subtraction (bounded S; clamp
            // makes inf impossible). li accumulates lane-locally.
#pragma unroll
            for (int ar = 0; ar < 2; ++ar)
#pragma unroll
                for (int r = 0; r < 4; ++r) {
                    float pv0 = __expf(fminf(s4[ar][0][r], 30.f));
                    float pv1 = __expf(fminf(s4[ar][1][r], 30.f));
                    float pv2 = __expf(fminf(s4[ar][2][r], 30.f));
                    float pv3 = __expf(fminf(s4[ar][3][r], 30.f));
                    li[ar][r] += (pv0 + pv1) + (pv2 + pv3);

                    int lrow = ar * 16 + (lane >> 4) * 4 + r;
                    int rb   = wv * 2048 + lrow * 64;
                    int k0c  = lane & 15;
                    Ps[rb + (((0 * 16 + k0c) >> 3) ^ (lrow & 7)) * 8 + (k0c & 7)] = f2bf(pv0);
                    Ps[rb + (((1 * 16 + k0c) >> 3) ^ (lrow & 7)) * 8 + (k0c & 7)] = f2bf(pv1);
                    Ps[rb + (((2 * 16 + k0c) >> 3) ^ (lrow & 7)) * 8 + (k0c & 7)] = f2bf(pv2);
                    Ps[rb + (((3 * 16 + k0c) >> 3) ^ (lrow & 7)) * 8 + (k0c & 7)] = f2bf(pv3);
                }

            // ---- O += P V  (k-dim = keys); P reads are wave-local
            __builtin_amdgcn_s_setprio(1);
#pragma unroll
            for (int ks = 0; ks < 2; ++ks) {
                bf16x8 ap[2];
#pragma unroll
                for (int ar = 0; ar < 2; ++ar) {
                    int arow = ar * 16 + (lane & 15);
                    int ac   = (ks * 4 + (lane >> 4)) ^ (arow & 7);
                    ap[ar] = *(const bf16x8*)&Ps[wv * 2048 + arow * 64 + ac * 8];
                }
#pragma unroll
                for (int df = 0; df < 4; ++df) {
                    int brow = df * 16 + (lane & 15);
                    int bc   = (ks * 4 + (lane >> 4)) ^ (brow & 7);
                    bf16x8 bv = *(const bf16x8*)&Vs[cur][brow * 64 + bc * 8];
#pragma unroll
                    for (int ar = 0; ar < 2; ++ar)
                        accO[ar][df] = __builtin_amdgcn_mfma_f32_16x16x32_bf16(
                            ap[ar], bv, accO[ar][df], 0, 0, 0);
                }
            }
            __builtin_amdgcn_s_setprio(0);
        }

        asm volatile("s_waitcnt vmcnt(0)" ::: "memory");
        __syncthreads();
        cur ^= 1;
    }

    // Epilogue: reduce deferred li partials across the 16-lane row group, once.
#pragma unroll
    for (int ar = 0; ar < 2; ++ar)
#pragma unroll
        for (int r = 0; r < 4; ++r) {
            float lsum = li[ar][r];
#pragma unroll
            for (int off = 8; off; off >>= 1)
                lsum += __shfl_xor(lsum, off, 16);
            float inv = 1.0f / lsum;
            int t = qb * 128 + wv * 32 + ar * 16 + (lane >> 4) * 4 + r;
#pragma unroll
            for (int df = 0; df < 4; ++df) {
                int d = df * 16 + (lane & 15);
                og[(tb + t) * 64 + d] = f2bf(accO[ar][df][r] * inv);
            }
        }
}

// ---------------------------------------------------------------------------
// Proj GEMM: gather(O [bh][t][64]) @ w_projT [1024][1024] + b -> out fp32
// Triple-buffer counted-vmcnt pipeline; R10: XCD-chunked swizzled 1D grid
// (512 = 8 x 64, n-major decode).
// ---------------------------------------------------------------------------
__global__ __launch_bounds__(256) void proj_gemm_bf16(
    const u16* __restrict__ ob, const u16* __restrict__ wT,
    const float* __restrict__ bias, float* __restrict__ out)
{
    __shared__ u16 At[3][4096];
    __shared__ u16 Bt[3][4096];

    const int tid  = threadIdx.x;
    const int lane = tid & 63;
    const int wv   = tid >> 6;
    const int wr   = wv >> 1;
    const int wc   = wv & 1;
    const int bsw  = (int)blockIdx.x;
    const int w    = (bsw & 7) * 64 + (bsw >> 3);    // XCD-chunked, bijective
    const int m0   = (w & 63) * 128;
    const int n0   = (w >> 6) * 128;

    const int p1 = wv * 128 + lane, p2 = p1 + 64;
    const int r1 = p1 >> 2, c1 = (p1 & 3) ^ ((r1 >> 1) & 3);
    const int r2 = p2 >> 2, c2 = (p2 & 3) ^ ((r2 >> 1) & 3);

    const int m1 = m0 + r1, m2 = m0 + r2;
    const size_t ab1 = ((size_t)(m1 >> 11) * Hc) * Tc + (m1 & 2047);
    const size_t ab2 = ((size_t)(m2 >> 11) * Hc) * Tc + (m2 & 2047);
    const u16* gb1 = wT + (size_t)(n0 + r1) * 1024 + c1 * 8;
    const u16* gb2 = wT + (size_t)(n0 + r2) * 1024 + c2 * 8;

    f32x4 acc[4][4] = {};

#define STAGE_P(buf, k0)                                                          \
    do {                                                                          \
        int kk1 = (k0) + c1 * 8, kk2 = (k0) + c2 * 8;                             \
        gld_lds16(ob + (ab1 + (size_t)(kk1 >> 6) * Tc) * 64 + (kk1 & 63),         \
                  &At[buf][wv * 1024]);                                           \
        gld_lds16(ob + (ab2 + (size_t)(kk2 >> 6) * Tc) * 64 + (kk2 & 63),         \
                  &At[buf][wv * 1024 + 512]);                                     \
        gld_lds16(gb1 + (k0), &Bt[buf][wv * 1024]);                               \
        gld_lds16(gb2 + (k0), &Bt[buf][wv * 1024 + 512]);                         \
    } while (0)

    auto COMPUTE = [&](int bsel) {
        bf16x8 af[4], bfr[4];
#pragma unroll
        for (int i = 0; i < 4; ++i) {
            int row = wr * 64 + i * 16 + (lane & 15);
            int c   = (lane >> 4) ^ ((row >> 1) & 3);
            af[i] = *(const bf16x8*)&At[bsel][row * 32 + c * 8];
            int rowb = wc * 64 + i * 16 + (lane & 15);
            int cb   = (lane >> 4) ^ ((rowb >> 1) & 3);
            bfr[i] = *(const bf16x8*)&Bt[bsel][rowb * 32 + cb * 8];
        }
#pragma unroll
        for (int i = 0; i < 4; ++i)
#pragma unroll
            for (int j = 0; j < 4; ++j)
                acc[i][j] = __builtin_amdgcn_mfma_f32_16x16x32_bf16(
                    af[i], bfr[j], acc[i][j], 0, 0, 0);
    };

    STAGE_P(0, 0);
    STAGE_P(1, 32);
    int b0 = 0, b1 = 1, b2 = 2;
    for (int t = 0; t < 31; ++t) {
        asm volatile("s_waitcnt vmcnt(4)" ::: "memory");
        __builtin_amdgcn_s_barrier();
        asm volatile("" ::: "memory");
        if (t < 30) STAGE_P(b2, (t + 2) * 32);
        COMPUTE(b0);
        int tmp = b0; b0 = b1; b1 = b2; b2 = tmp;
    }
    asm volatile("s_waitcnt vmcnt(0)" ::: "memory");
    __builtin_amdgcn_s_barrier();
    asm volatile("" ::: "memory");
    COMPUTE(b0);
#undef STAGE_P

    const int rr = (lane >> 4) * 4;
    const int cl = lane & 15;
#pragma unroll
    for (int i = 0; i < 4; ++i)
#pragma unroll
        for (int j = 0; j < 4; ++j) {
            int n = n0 + wc * 64 + j * 16 + cl;
            float bv = bias[n];
#pragma unroll
            for (int r = 0; r < 4; ++r) {
                int m = m0 + wr * 64 + i * 16 + rr + r;
                out[(size_t)m * 1024 + n] = acc[i][j][r] + bv;
            }
        }
}

// ---------------------------------------------------------------------------
extern "C" void kernel_launch(void* const* d_in, const int* in_sizes, int n_in,
                              void* d_out, int out_size, void* d_ws, size_t ws_size,
                              hipStream_t stream) {
    const float* x      = (const float*)d_in[0];
    const float* w_qkv  = (const float*)d_in[1];
    const float* b_qkv  = (const float*)d_in[2];
    const float* w_proj = (const float*)d_in[3];
    const float* b_proj = (const float*)d_in[4];
    float* out = (float*)d_out;

    u16* xb     = (u16*)d_ws;            // 16 MiB
    u16* wqkvT  = xb + QE;               // 6 MiB
    u16* wprojT = wqkvT + 3145728;       // 2 MiB
    u16* qb16   = wprojT + 1048576;      // 16 MiB
    u16* kb16   = qb16 + QE;             // 16 MiB
    u16* vtb    = kb16 + QE;             // 16 MiB (V transposed [bh][d][t])
    u16* ob16   = vtb + QE;              // 16 MiB — total 88 MiB

    cvt_fused<<<5120, 256, 0, stream>>>(x, w_qkv, w_proj, xb, wqkvT, wprojT);
    qkv_gemm_bf16<<<1536, 256, 0, stream>>>(xb, wqkvT, b_qkv, qb16, kb16, vtb);
    flash_mfma<<<1024, 256, 0, stream>>>(qb16, kb16, vtb, ob16);
    proj_gemm_bf16<<<512, 256, 0, stream>>>(ob16, wprojT, b_proj, out);
}

// Round 12
// 263.600 us; speedup vs baseline: 1.0874x; 1.0874x over previous
//
#include <hip/hip_runtime.h>
#include <math.h>
#include <stdint.h>

typedef unsigned short u16;
typedef __bf16 bf16x8 __attribute__((ext_vector_type(8)));
typedef float  f32x4  __attribute__((ext_vector_type(4)));

#define AS1 __attribute__((address_space(1)))
#define AS3 __attribute__((address_space(3)))

__device__ __forceinline__ void gld_lds16(const void* g, void* l) {
    // async global->LDS, 16B per lane; LDS dest = wave-uniform base + lane*16
    __builtin_amdgcn_global_load_lds((AS1 const uint32_t*)g, (AS3 uint32_t*)l, 16, 0, 0);
}

__device__ __forceinline__ u16 f2bf(float f) {   // RNE
    unsigned u = __float_as_uint(f);
    unsigned r = u + 0x7fffu + ((u >> 16) & 1u);
    return (u16)(r >> 16);
}

namespace {
constexpr int Tc  = 2048;
constexpr int Hc  = 16;
constexpr size_t QE = 8388608;   // B*H*T*64 elems
}

// ---------------------------------------------------------------------------
// Fused converts (1 launch instead of 3):
//   blocks 0..4095   : x fp32 -> bf16 flat (8 elems/thread, exact cover)
//   blocks 4096..4863: w_qkv  [1024][3072] -> bf16 [3072][1024] transpose
//   blocks 4864..5119: w_proj [1024][1024] -> bf16 [1024][1024] transpose
// ---------------------------------------------------------------------------
__global__ __launch_bounds__(256) void cvt_fused(
    const float* __restrict__ x, const float* __restrict__ wq,
    const float* __restrict__ wp,
    u16* __restrict__ xb, u16* __restrict__ wqT, u16* __restrict__ wpT)
{
    __shared__ u16 t[64][72];
    const int b   = blockIdx.x;
    const int tid = threadIdx.x;

    if (b < 4096) {   // flat convert: 4096*256 threads == 1048576 == exact
        int i = b * 256 + tid;
        const float4* p = (const float4*)x + (size_t)i * 2;
        float4 a = p[0], bb = p[1];
        union { u16 u[8]; uint4 v; } r;
        r.u[0] = f2bf(a.x);  r.u[1] = f2bf(a.y);
        r.u[2] = f2bf(a.z);  r.u[3] = f2bf(a.w);
        r.u[4] = f2bf(bb.x); r.u[5] = f2bf(bb.y);
        r.u[6] = f2bf(bb.z); r.u[7] = f2bf(bb.w);
        ((uint4*)xb)[i] = r.v;
        return;
    }

    const float* src;
    u16* dst;
    int N, bx, by;
    if (b < 4864) { int l = b - 4096; N = 3072; src = wq; dst = wqT; bx = l % 48; by = l / 48; }
    else          { int l = b - 4864; N = 1024; src = wp; dst = wpT; bx = l % 16; by = l / 16; }

    const int n0 = bx * 64, k0 = by * 64;
    const int r  = tid >> 2, c0 = (tid & 3) << 4;
    const float* s = src + (size_t)(k0 + r) * N + n0 + c0;
#pragma unroll
    for (int j = 0; j < 16; j += 4) {
        float4 f = *(const float4*)(s + j);
        t[r][c0 + j + 0] = f2bf(f.x);
        t[r][c0 + j + 1] = f2bf(f.y);
        t[r][c0 + j + 2] = f2bf(f.z);
        t[r][c0 + j + 3] = f2bf(f.w);
    }
    __syncthreads();
    u16* d = dst + (size_t)(n0 + r) * 1024 + k0 + c0;
    union { u16 u[8]; uint4 v; } o1, o2;
#pragma unroll
    for (int j = 0; j < 8; ++j) o1.u[j] = t[c0 + j][r];
#pragma unroll
    for (int j = 0; j < 8; ++j) o2.u[j] = t[c0 + 8 + j][r];
    *(uint4*)d = o1.v;
    *(uint4*)(d + 8) = o2.v;
}

// ---------------------------------------------------------------------------
// QKV GEMM: [8192,1024]bf16 @ [1024,3072] (B^T layout [3072][1024]) -> q/k/vT
// 128x128 tile, BK=32, 4 waves, 16x16x32 MFMA.
// Triple-buffer LDS + counted s_waitcnt vmcnt(4) + raw s_barrier.
// Grid swizzle REVERTED (R10: n-major XCD chunks streamed ALL of A
// through every XCD's L2 -> FETCH 49->200 MB, dur +15%. Default 2D order
// keeps all XCDs on one B-panel at a time: only the 256KB panel duplicates).
// ---------------------------------------------------------------------------
__global__ __launch_bounds__(256) void qkv_gemm_bf16(
    const u16* __restrict__ xb, const u16* __restrict__ wT,
    const float* __restrict__ bias,
    u16* __restrict__ qo, u16* __restrict__ ko, u16* __restrict__ vt)
{
    __shared__ u16 At[3][4096];
    __shared__ u16 Bt[3][4096];

    const int tid  = threadIdx.x;
    const int lane = tid & 63;
    const int wv   = tid >> 6;
    const int wr   = wv >> 1;
    const int wc   = wv & 1;
    const int m0   = blockIdx.x * 128;
    const int n0   = blockIdx.y * 128;

    const int p1 = wv * 128 + lane, p2 = p1 + 64;
    const int r1 = p1 >> 2, c1 = (p1 & 3) ^ ((r1 >> 1) & 3);
    const int r2 = p2 >> 2, c2 = (p2 & 3) ^ ((r2 >> 1) & 3);

    const u16* ga1 = xb + (size_t)(m0 + r1) * 1024 + c1 * 8;
    const u16* ga2 = xb + (size_t)(m0 + r2) * 1024 + c2 * 8;
    const u16* gb1 = wT + (size_t)(n0 + r1) * 1024 + c1 * 8;
    const u16* gb2 = wT + (size_t)(n0 + r2) * 1024 + c2 * 8;

    f32x4 acc[4][4] = {};

#define STAGE_G(buf, k0)                                   \
    do {                                                   \
        gld_lds16(ga1 + (k0), &At[buf][wv * 1024]);        \
        gld_lds16(ga2 + (k0), &At[buf][wv * 1024 + 512]);  \
        gld_lds16(gb1 + (k0), &Bt[buf][wv * 1024]);        \
        gld_lds16(gb2 + (k0), &Bt[buf][wv * 1024 + 512]);  \
    } while (0)

    auto COMPUTE = [&](int bsel) {
        bf16x8 af[4], bfr[4];
#pragma unroll
        for (int i = 0; i < 4; ++i) {
            int row = wr * 64 + i * 16 + (lane & 15);
            int c   = (lane >> 4) ^ ((row >> 1) & 3);
            af[i] = *(const bf16x8*)&At[bsel][row * 32 + c * 8];
            int rowb = wc * 64 + i * 16 + (lane & 15);
            int cb   = (lane >> 4) ^ ((rowb >> 1) & 3);
            bfr[i] = *(const bf16x8*)&Bt[bsel][rowb * 32 + cb * 8];
        }
#pragma unroll
        for (int i = 0; i < 4; ++i)
#pragma unroll
            for (int j = 0; j < 4; ++j)
                acc[i][j] = __builtin_amdgcn_mfma_f32_16x16x32_bf16(
                    af[i], bfr[j], acc[i][j], 0, 0, 0);
    };

    STAGE_G(0, 0);
    STAGE_G(1, 32);
    int b0 = 0, b1 = 1, b2 = 2;
    for (int t = 0; t < 31; ++t) {
        asm volatile("s_waitcnt vmcnt(4)" ::: "memory");  // own stage(t) landed
        __builtin_amdgcn_s_barrier();                     // everyone's landed
        asm volatile("" ::: "memory");
        if (t < 30) STAGE_G(b2, (t + 2) * 32);
        COMPUTE(b0);
        int tmp = b0; b0 = b1; b1 = b2; b2 = tmp;
    }
    asm volatile("s_waitcnt vmcnt(0)" ::: "memory");
    __builtin_amdgcn_s_barrier();
    asm volatile("" ::: "memory");
    COMPUTE(b0);
#undef STAGE_G

    const int nq = n0 + wc * 64;
    const int which = nq >> 10;
    const int h  = (nq & 1023) >> 6;
    const int rr = (lane >> 4) * 4;
    const int cl = lane & 15;

    if (which < 2) {
        u16* dst = which ? ko : qo;
#pragma unroll
        for (int i = 0; i < 4; ++i)
#pragma unroll
            for (int j = 0; j < 4; ++j) {
                int d = j * 16 + cl;
                float bv = bias[nq + d];
#pragma unroll
                for (int r = 0; r < 4; ++r) {
                    int m = m0 + wr * 64 + i * 16 + rr + r;
                    int b = m >> 11, tt = m & 2047;
                    dst[(((size_t)(b * Hc + h)) * Tc + tt) * 64 + d] =
                        f2bf(acc[i][j][r] + bv);
                }
            }
    } else {
        // V stored TRANSPOSED: vt[bh][d][t]
#pragma unroll
        for (int i = 0; i < 4; ++i) {
            int m = m0 + wr * 64 + i * 16 + rr;
            int b = m >> 11, tt = m & 2047;
#pragma unroll
            for (int j = 0; j < 4; ++j) {
                int d = j * 16 + cl;
                float bv = bias[nq + d];
                union { u16 u[4]; uint2 v2; } pk;
#pragma unroll
                for (int r = 0; r < 4; ++r) pk.u[r] = f2bf(acc[i][j][r] + bv);
                *(uint2*)&vt[((size_t)(b * Hc + h) * 64 + d) * Tc + tt] = pk.v2;
            }
        }
    }
}

// ---------------------------------------------------------------------------
// Flash attention v5: 128 q-rows/block (32/wave), Q pre-scaled in registers,
// K/V dbuf swizzled LDS, setprio around MFMA, max-free softmax (bounded S),
// lane-local deferred li.
// ---------------------------------------------------------------------------
__global__ __launch_bounds__(256, 3) void flash_mfma(
    const u16* __restrict__ qg, const u16* __restrict__ kg,
    const u16* __restrict__ vtg, u16* __restrict__ og)
{
    __shared__ u16 Ks[2][4096];
    __shared__ u16 Vs[2][4096];
    __shared__ u16 Ps[8192];     // 4 waves x 32 rows x 64 (swizzled)

    const int tid  = threadIdx.x;
    const int lane = tid & 63;
    const int wv   = tid >> 6;
    const int qb   = 15 - (int)(blockIdx.x >> 6);   // qb-major, heavy first
    const int bh   = blockIdx.x & 63;

    const int p1 = wv * 128 + lane, p2 = p1 + 64;
    const int r1 = p1 >> 3, c1 = (p1 & 7) ^ (r1 & 7);
    const int r2 = p2 >> 3, c2 = (p2 & 7) ^ (r2 & 7);

    const size_t tb = (size_t)bh * Tc;
    const u16* kb1 = kg + (tb + r1) * 64 + c1 * 8;
    const u16* kb2 = kg + (tb + r2) * 64 + c2 * 8;
    const u16* vb1 = vtg + ((size_t)bh * 64 + r1) * Tc + c1 * 8;
    const u16* vb2 = vtg + ((size_t)bh * 64 + r2) * Tc + c2 * 8;

    // ---- Q -> registers, pre-scaled by 1/8 (exact in bf16)
    bf16x8 qr[2][2];
    {
        const u16* qbase = qg + (tb + (size_t)qb * 128 + wv * 32) * 64;
#pragma unroll
        for (int ar = 0; ar < 2; ++ar)
#pragma unroll
            for (int ks = 0; ks < 2; ++ks) {
                union { bf16x8 v; u16 u[8]; uint4 q; } t;
                t.q = *(const uint4*)(qbase + (ar * 16 + (lane & 15)) * 64 +
                                      ks * 32 + (lane >> 4) * 8);
#pragma unroll
                for (int j = 0; j < 8; ++j) {
                    float f = __uint_as_float((unsigned)t.u[j] << 16) * 0.125f;
                    t.u[j] = f2bf(f);
                }
                qr[ar][ks] = t.v;
            }
    }

    gld_lds16(kb1, &Ks[0][wv * 1024]);
    gld_lds16(kb2, &Ks[0][wv * 1024 + 512]);
    gld_lds16(vb1, &Vs[0][wv * 1024]);
    gld_lds16(vb2, &Vs[0][wv * 1024 + 512]);
    asm volatile("s_waitcnt vmcnt(0)" ::: "memory");
    __syncthreads();

    f32x4 accO[2][4] = {};
    float li[2][4] = {};

    const int nt = 2 * qb + 2;
    int cur = 0;

    for (int kt = 0; kt < nt; ++kt) {
        if (kt + 1 < nt) {
            int nx = kt + 1;
            gld_lds16(kb1 + (size_t)nx * 4096, &Ks[cur ^ 1][wv * 1024]);
            gld_lds16(kb2 + (size_t)nx * 4096, &Ks[cur ^ 1][wv * 1024 + 512]);
            gld_lds16(vb1 + nx * 64, &Vs[cur ^ 1][wv * 1024]);
            gld_lds16(vb2 + nx * 64, &Vs[cur ^ 1][wv * 1024 + 512]);
        }

        // waves 0/1 are fully masked on the final (odd) diagonal tile
        const bool skip = (kt == 2 * qb + 1) && (wv < 2);
        if (!skip) {
            // ---- S = Q K^T : per wave 32 q-rows x 64 keys
            f32x4 s4[2][4] = {};
            __builtin_amdgcn_s_setprio(1);
#pragma unroll
            for (int ks = 0; ks < 2; ++ks) {
                bf16x8 bk[4];
#pragma unroll
                for (int nf = 0; nf < 4; ++nf) {
                    int brow = nf * 16 + (lane & 15);
                    int bc   = (ks * 4 + (lane >> 4)) ^ (brow & 7);
                    bk[nf] = *(const bf16x8*)&Ks[cur][brow * 64 + bc * 8];
                }
#pragma unroll
                for (int ar = 0; ar < 2; ++ar)
#pragma unroll
                    for (int nf = 0; nf < 4; ++nf)
                        s4[ar][nf] = __builtin_amdgcn_mfma_f32_16x16x32_bf16(
                            qr[ar][ks], bk[nf], s4[ar][nf], 0, 0, 0);
            }
            __builtin_amdgcn_s_setprio(0);

            if (kt >= 2 * qb) {   // diagonal region: mask key > q
#pragma unroll
                for (int ar = 0; ar < 2; ++ar)
#pragma unroll
                    for (int nf = 0; nf < 4; ++nf)
#pragma unroll
                        for (int r = 0; r < 4; ++r) {
                            int key  = kt * 64 + nf * 16 + (lane & 15);
                            int qrow = qb * 128 + wv * 32 + ar * 16 +
                                       (lane >> 4) * 4 + r;
                            if (key > qrow) s4[ar][nf][r] = -INFINITY;
                        }
            }

            // ---- softmax numerator, no max subtraction (bounded S; clamp
            // makes inf impossible). li accumulates lane-locally.
#pragma unroll
            for (int ar = 0; ar < 2; ++ar)
#pragma unroll
                for (int r = 0; r < 4; ++r) {
                    float pv0 = __expf(fminf(s4[ar][0][r], 30.f));
                    float pv1 = __expf(fminf(s4[ar][1][r], 30.f));
                    float pv2 = __expf(fminf(s4[ar][2][r], 30.f));
                    float pv3 = __expf(fminf(s4[ar][3][r], 30.f));
                    li[ar][r] += (pv0 + pv1) + (pv2 + pv3);

                    int lrow = ar * 16 + (lane >> 4) * 4 + r;
                    int rb   = wv * 2048 + lrow * 64;
                    int k0c  = lane & 15;
                    Ps[rb + (((0 * 16 + k0c) >> 3) ^ (lrow & 7)) * 8 + (k0c & 7)] = f2bf(pv0);
                    Ps[rb + (((1 * 16 + k0c) >> 3) ^ (lrow & 7)) * 8 + (k0c & 7)] = f2bf(pv1);
                    Ps[rb + (((2 * 16 + k0c) >> 3) ^ (lrow & 7)) * 8 + (k0c & 7)] = f2bf(pv2);
                    Ps[rb + (((3 * 16 + k0c) >> 3) ^ (lrow & 7)) * 8 + (k0c & 7)] = f2bf(pv3);
                }

            // ---- O += P V  (k-dim = keys); P reads are wave-local
            __builtin_amdgcn_s_setprio(1);
#pragma unroll
            for (int ks = 0; ks < 2; ++ks) {
                bf16x8 ap[2];
#pragma unroll
                for (int ar = 0; ar < 2; ++ar) {
                    int arow = ar * 16 + (lane & 15);
                    int ac   = (ks * 4 + (lane >> 4)) ^ (arow & 7);
                    ap[ar] = *(const bf16x8*)&Ps[wv * 2048 + arow * 64 + ac * 8];
                }
#pragma unroll
                for (int df = 0; df < 4; ++df) {
                    int brow = df * 16 + (lane & 15);
                    int bc   = (ks * 4 + (lane >> 4)) ^ (brow & 7);
                    bf16x8 bv = *(const bf16x8*)&Vs[cur][brow * 64 + bc * 8];
#pragma unroll
                    for (int ar = 0; ar < 2; ++ar)
                        accO[ar][df] = __builtin_amdgcn_mfma_f32_16x16x32_bf16(
                            ap[ar], bv, accO[ar][df], 0, 0, 0);
                }
            }
            __builtin_amdgcn_s_setprio(0);
        }

        asm volatile("s_waitcnt vmcnt(0)" ::: "memory");
        __syncthreads();
        cur ^= 1;
    }

    // Epilogue: reduce deferred li partials across the 16-lane row group, once.
#pragma unroll
    for (int ar = 0; ar < 2; ++ar)
#pragma unroll
        for (int r = 0; r < 4; ++r) {
            float lsum = li[ar][r];
#pragma unroll
            for (int off = 8; off; off >>= 1)
                lsum += __shfl_xor(lsum, off, 16);
            float inv = 1.0f / lsum;
            int t = qb * 128 + wv * 32 + ar * 16 + (lane >> 4) * 4 + r;
#pragma unroll
            for (int df = 0; df < 4; ++df) {
                int d = df * 16 + (lane & 15);
                og[(tb + t) * 64 + d] = f2bf(accO[ar][df][r] * inv);
            }
        }
}

// ---------------------------------------------------------------------------
// Proj GEMM: gather(O [bh][t][64]) @ w_projT [1024][1024] + b -> out fp32
// Triple-buffer counted-vmcnt pipeline; 2D grid (swizzle reverted, see qkv).
// ---------------------------------------------------------------------------
__global__ __launch_bounds__(256) void proj_gemm_bf16(
    const u16* __restrict__ ob, const u16* __restrict__ wT,
    const float* __restrict__ bias, float* __restrict__ out)
{
    __shared__ u16 At[3][4096];
    __shared__ u16 Bt[3][4096];

    const int tid  = threadIdx.x;
    const int lane = tid & 63;
    const int wv   = tid >> 6;
    const int wr   = wv >> 1;
    const int wc   = wv & 1;
    const int m0   = blockIdx.x * 128;
    const int n0   = blockIdx.y * 128;

    const int p1 = wv * 128 + lane, p2 = p1 + 64;
    const int r1 = p1 >> 2, c1 = (p1 & 3) ^ ((r1 >> 1) & 3);
    const int r2 = p2 >> 2, c2 = (p2 & 3) ^ ((r2 >> 1) & 3);

    const int m1 = m0 + r1, m2 = m0 + r2;
    const size_t ab1 = ((size_t)(m1 >> 11) * Hc) * Tc + (m1 & 2047);
    const size_t ab2 = ((size_t)(m2 >> 11) * Hc) * Tc + (m2 & 2047);
    const u16* gb1 = wT + (size_t)(n0 + r1) * 1024 + c1 * 8;
    const u16* gb2 = wT + (size_t)(n0 + r2) * 1024 + c2 * 8;

    f32x4 acc[4][4] = {};

#define STAGE_P(buf, k0)                                                          \
    do {                                                                          \
        int kk1 = (k0) + c1 * 8, kk2 = (k0) + c2 * 8;                             \
        gld_lds16(ob + (ab1 + (size_t)(kk1 >> 6) * Tc) * 64 + (kk1 & 63),         \
                  &At[buf][wv * 1024]);                                           \
        gld_lds16(ob + (ab2 + (size_t)(kk2 >> 6) * Tc) * 64 + (kk2 & 63),         \
                  &At[buf][wv * 1024 + 512]);                                     \
        gld_lds16(gb1 + (k0), &Bt[buf][wv * 1024]);                               \
        gld_lds16(gb2 + (k0), &Bt[buf][wv * 1024 + 512]);                         \
    } while (0)

    auto COMPUTE = [&](int bsel) {
        bf16x8 af[4], bfr[4];
#pragma unroll
        for (int i = 0; i < 4; ++i) {
            int row = wr * 64 + i * 16 + (lane & 15);
            int c   = (lane >> 4) ^ ((row >> 1) & 3);
            af[i] = *(const bf16x8*)&At[bsel][row * 32 + c * 8];
            int rowb = wc * 64 + i * 16 + (lane & 15);
            int cb   = (lane >> 4) ^ ((rowb >> 1) & 3);
            bfr[i] = *(const bf16x8*)&Bt[bsel][rowb * 32 + cb * 8];
        }
#pragma unroll
        for (int i = 0; i < 4; ++i)
#pragma unroll
            for (int j = 0; j < 4; ++j)
                acc[i][j] = __builtin_amdgcn_mfma_f32_16x16x32_bf16(
                    af[i], bfr[j], acc[i][j], 0, 0, 0);
    };

    STAGE_P(0, 0);
    STAGE_P(1, 32);
    int b0 = 0, b1 = 1, b2 = 2;
    for (int t = 0; t < 31; ++t) {
        asm volatile("s_waitcnt vmcnt(4)" ::: "memory");
        __builtin_amdgcn_s_barrier();
        asm volatile("" ::: "memory");
        if (t < 30) STAGE_P(b2, (t + 2) * 32);
        COMPUTE(b0);
        int tmp = b0; b0 = b1; b1 = b2; b2 = tmp;
    }
    asm volatile("s_waitcnt vmcnt(0)" ::: "memory");
    __builtin_amdgcn_s_barrier();
    asm volatile("" ::: "memory");
    COMPUTE(b0);
#undef STAGE_P

    const int rr = (lane >> 4) * 4;
    const int cl = lane & 15;
#pragma unroll
    for (int i = 0; i < 4; ++i)
#pragma unroll
        for (int j = 0; j < 4; ++j) {
            int n = n0 + wc * 64 + j * 16 + cl;
            float bv = bias[n];
#pragma unroll
            for (int r = 0; r < 4; ++r) {
                int m = m0 + wr * 64 + i * 16 + rr + r;
                out[(size_t)m * 1024 + n] = acc[i][j][r] + bv;
            }
        }
}

// ---------------------------------------------------------------------------
extern "C" void kernel_launch(void* const* d_in, const int* in_sizes, int n_in,
                              void* d_out, int out_size, void* d_ws, size_t ws_size,
                              hipStream_t stream) {
    const float* x      = (const float*)d_in[0];
    const float* w_qkv  = (const float*)d_in[1];
    const float* b_qkv  = (const float*)d_in[2];
    const float* w_proj = (const float*)d_in[3];
    const float* b_proj = (const float*)d_in[4];
    float* out = (float*)d_out;

    u16* xb     = (u16*)d_ws;            // 16 MiB
    u16* wqkvT  = xb + QE;               // 6 MiB
    u16* wprojT = wqkvT + 3145728;       // 2 MiB
    u16* qb16   = wprojT + 1048576;      // 16 MiB
    u16* kb16   = qb16 + QE;             // 16 MiB
    u16* vtb    = kb16 + QE;             // 16 MiB (V transposed [bh][d][t])
    u16* ob16   = vtb + QE;              // 16 MiB — total 88 MiB

    cvt_fused<<<5120, 256, 0, stream>>>(x, w_qkv, w_proj, xb, wqkvT, wprojT);
    qkv_gemm_bf16<<<dim3(64, 24), 256, 0, stream>>>(xb, wqkvT, b_qkv, qb16, kb16, vtb);
    flash_mfma<<<1024, 256, 0, stream>>>(qb16, kb16, vtb, ob16);
    proj_gemm_bf16<<<dim3(64, 8), 256, 0, stream>>>(ob16, wprojT, b_proj, out);
}